// Round 7
// baseline (2950.366 us; speedup 1.0000x reference)
//
#include <hip/hip_runtime.h>
#include <hip/hip_bf16.h>

__device__ __forceinline__ float sigmoidf_(float x) {
    return 1.0f / (1.0f + __expf(-x));
}
__device__ __forceinline__ float tanhf_(float x) {
    float e = __expf(2.0f * x);
    return 1.0f - 2.0f / (e + 1.0f);
}

// ---------------------------------------------------------------------------
// h0[node] = GRU step with hprev=0:  gi = h@Wih.T+bih; gh = bhh
// ---------------------------------------------------------------------------
__global__ __launch_bounds__(256) void compute_h0(
    const float* __restrict__ h, const float* __restrict__ Wih,
    const float* __restrict__ bih, const float* __restrict__ bhh,
    float* __restrict__ h0, int n1)
{
    int node = blockIdx.x * 256 + threadIdx.x;
    if (node >= n1) return;
    float x[32];
    const float4* hx = (const float4*)(h + (size_t)node * 32);
#pragma unroll
    for (int c = 0; c < 8; ++c) {
        float4 v = hx[c];
        x[c*4+0] = v.x; x[c*4+1] = v.y; x[c*4+2] = v.z; x[c*4+3] = v.w;
    }
    float o[32];
#pragma unroll
    for (int j = 0; j < 32; ++j) {
        float ir = bih[j], iz = bih[32 + j], in_ = bih[64 + j];
#pragma unroll
        for (int i = 0; i < 32; ++i) {
            ir  += x[i] * Wih[j * 32 + i];
            iz  += x[i] * Wih[(32 + j) * 32 + i];
            in_ += x[i] * Wih[(64 + j) * 32 + i];
        }
        float r = sigmoidf_(ir + bhh[j]);
        float z = sigmoidf_(iz + bhh[32 + j]);
        float n = tanhf_(in_ + r * bhh[64 + j]);
        o[j] = (1.0f - z) * n;
    }
    float4* dst = (float4*)(h0 + (size_t)node * 32);
#pragma unroll
    for (int c = 0; c < 8; ++c)
        dst[c] = make_float4(o[c*4+0], o[c*4+1], o[c*4+2], o[c*4+3]);
}

// ---------------------------------------------------------------------------
// Batched histogram per k-list: col 0 -> cnt0, cols t>=1 -> counts[(t-1)*n1+]
// ---------------------------------------------------------------------------
template <int K>
__global__ __launch_bounds__(256) void hist_all(
    const int* __restrict__ idx, int nI, int* __restrict__ cnt0,
    int* __restrict__ counts, int n1)
{
    int i = blockIdx.x * 256 + threadIdx.x;
    if (i >= nI) return;
    int t = i % K;
    int node = idx[i];
    if (t == 0) atomicAdd(&cnt0[node], 1);
    else        atomicAdd(&counts[(size_t)(t - 1) * n1 + node], 1);
}

// ---------------------------------------------------------------------------
// Scan machinery (3-level): scan_block inclusive, scan_bsums -> exclusive
// ---------------------------------------------------------------------------
__global__ __launch_bounds__(256) void scan_block(
    const int* __restrict__ in, int* __restrict__ incl,
    int* __restrict__ bsums, int n)
{
    __shared__ int s[256];
    int i = blockIdx.x * 256 + threadIdx.x;
    int v = (i < n) ? in[i] : 0;
    s[threadIdx.x] = v;
    __syncthreads();
    for (int d = 1; d < 256; d <<= 1) {
        int tt = (threadIdx.x >= d) ? s[threadIdx.x - d] : 0;
        __syncthreads();
        s[threadIdx.x] += tt;
        __syncthreads();
    }
    if (i < n) incl[i] = s[threadIdx.x];
    if (threadIdx.x == 255) bsums[blockIdx.x] = s[255];
}

__global__ __launch_bounds__(1024) void scan_bsums(int* bsums, int nb)
{
    __shared__ int s[1024];
    int v = (threadIdx.x < nb) ? bsums[threadIdx.x] : 0;
    s[threadIdx.x] = v;
    __syncthreads();
    for (int d = 1; d < 1024; d <<= 1) {
        int tt = (threadIdx.x >= d) ? s[threadIdx.x - d] : 0;
        __syncthreads();
        s[threadIdx.x] += tt;
        __syncthreads();
    }
    if (threadIdx.x < nb) bsums[threadIdx.x] = s[threadIdx.x] - v; // exclusive
}

// offs[i] (in-place over incl0) = global EXCLUSIVE prefix of counts
__global__ __launch_bounds__(256) void finalize_joint(
    int* __restrict__ offs, const int* __restrict__ counts,
    const int* __restrict__ bsums0, const int* __restrict__ incl1,
    const int* __restrict__ bsums1ex, int M)
{
    int i = blockIdx.x * 256 + threadIdx.x;
    if (i >= M) return;
    int b0 = i >> 8, b1 = b0 >> 8;
    offs[i] = offs[i] - counts[i] + (incl1[b0] - bsums0[b0]) + bsums1ex[b1];
}

// ---------------------------------------------------------------------------
// Batched ticket fill for columns t>=1 of a k-list
// ---------------------------------------------------------------------------
template <int K>
__global__ __launch_bounds__(256) void fill_all(
    const int* __restrict__ idx, int nW,   // nW = nE*(K-1)
    int* __restrict__ cursor, int* __restrict__ ent, int n1)
{
    int i = blockIdx.x * 256 + threadIdx.x;
    if (i >= nW) return;
    int e = i / (K - 1), tt = i % (K - 1);
    int node = idx[(size_t)e * K + tt + 1];
    int p = atomicAdd(&cursor[(size_t)tt * n1 + node], 1);
    ent[p] = e;
}

// ---------------------------------------------------------------------------
// One GRU step (t = T >= 1), gathering x from h and (T==1) hv from h0.
// ---------------------------------------------------------------------------
template <int K, int T>
__global__ __launch_bounds__(256) void gru_step_h(
    const int* __restrict__ idx, int nE,
    const float* __restrict__ h, const float* __restrict__ h0,
    const float* __restrict__ Wih, const float* __restrict__ bih,
    const float* __restrict__ Whh, const float* __restrict__ bhh,
    float* __restrict__ hstate)
{
    int e = blockIdx.x * 256 + threadIdx.x;
    if (e >= nE) return;

    float hv[32];
    if (T == 1) {
        int np = idx[(size_t)e * K];
        const float4* hp = (const float4*)(h0 + (size_t)np * 32);
#pragma unroll
        for (int c = 0; c < 8; ++c) {
            float4 v = hp[c];
            hv[c*4+0] = v.x; hv[c*4+1] = v.y; hv[c*4+2] = v.z; hv[c*4+3] = v.w;
        }
    } else {
        const float4* hp = (const float4*)(hstate + (size_t)e * 32);
#pragma unroll
        for (int c = 0; c < 8; ++c) {
            float4 v = hp[c];
            hv[c*4+0] = v.x; hv[c*4+1] = v.y; hv[c*4+2] = v.z; hv[c*4+3] = v.w;
        }
    }

    int node = idx[(size_t)e * K + T];
    float x[32];
    {
        const float4* hx = (const float4*)(h + (size_t)node * 32);
#pragma unroll
        for (int c = 0; c < 8; ++c) {
            float4 v = hx[c];
            x[c*4+0] = v.x; x[c*4+1] = v.y; x[c*4+2] = v.z; x[c*4+3] = v.w;
        }
    }

    float hn[32];
#pragma unroll
    for (int j = 0; j < 32; ++j) {
        float ir = bih[j], iz = bih[32 + j], in_ = bih[64 + j];
        float hr = bhh[j], hz = bhh[32 + j], hn2 = bhh[64 + j];
#pragma unroll
        for (int i = 0; i < 32; ++i) {
            ir  += x[i]  * Wih[j * 32 + i];
            iz  += x[i]  * Wih[(32 + j) * 32 + i];
            in_ += x[i]  * Wih[(64 + j) * 32 + i];
            hr  += hv[i] * Whh[j * 32 + i];
            hz  += hv[i] * Whh[(32 + j) * 32 + i];
            hn2 += hv[i] * Whh[(64 + j) * 32 + i];
        }
        float r = sigmoidf_(ir + hr);
        float z = sigmoidf_(iz + hz);
        float n = tanhf_(in_ + r * hn2);
        hn[j] = (1.0f - z) * n + z * hv[j];
    }
    float4* hs = (float4*)(hstate + (size_t)e * 32);
#pragma unroll
    for (int c = 0; c < 8; ++c)
        hs[c] = make_float4(hn[c*4+0], hn[c*4+1], hn[c*4+2], hn[c*4+3]);
}

// ---------------------------------------------------------------------------
// hkk[node] = cnt0[node] * h0[node]   (column-0 contribution, no gather)
// ---------------------------------------------------------------------------
__global__ __launch_bounds__(256) void init_hkk(
    const int* __restrict__ cnt0, const float* __restrict__ h0,
    float* __restrict__ hkk, int n1)
{
    int gid = blockIdx.x * 256 + threadIdx.x;
    int node = gid >> 3;
    int sub = gid & 7;
    if (node >= n1) return;
    float c = (float)cnt0[node];
    float4 v = *(const float4*)(h0 + (size_t)node * 32 + sub * 4);
    v.x *= c; v.y *= c; v.z *= c; v.w *= c;
    *(float4*)(hkk + (size_t)node * 32 + sub * 4) = v;
}

// ---------------------------------------------------------------------------
// hkk[node] += sum over entries of hstate rows. 8 threads/node, no atomics.
// end comes from cursor (== next offset after fill).
// ---------------------------------------------------------------------------
__global__ __launch_bounds__(256) void gather_add(
    const int* __restrict__ offs, const int* __restrict__ endp,
    const int* __restrict__ ent,
    const float* __restrict__ hstate, float* __restrict__ hkk, int n1)
{
    int gid = blockIdx.x * 256 + threadIdx.x;
    int node = gid >> 3;
    int sub = gid & 7;
    if (node >= n1) return;
    int beg = offs[node], end = endp[node];
    if (beg == end) return;
    float4 a = make_float4(0.f, 0.f, 0.f, 0.f);
    for (int p = beg; p < end; ++p) {
        int e = ent[p];
        float4 v = *(const float4*)(hstate + (size_t)e * 32 + sub * 4);
        a.x += v.x; a.y += v.y; a.z += v.z; a.w += v.w;
    }
    float* dst = hkk + (size_t)node * 32 + sub * 4;
    float4 cur = *(float4*)dst;
    cur.x += a.x; cur.y += a.y; cur.z += a.z; cur.w += a.w;
    *(float4*)dst = cur;
}

// ---------------------------------------------------------------------------
// acc(=out)[node] = b1 + h[node] @ W1[:,0:32].T
// ---------------------------------------------------------------------------
__global__ __launch_bounds__(256) void init_acc(
    const float* __restrict__ h, const float* __restrict__ W1,
    const float* __restrict__ b1, float* __restrict__ acc, int n1)
{
    int node = blockIdx.x * 256 + threadIdx.x;
    if (node >= n1) return;
    float x[32];
    const float4* hx = (const float4*)(h + (size_t)node * 32);
#pragma unroll
    for (int c = 0; c < 8; ++c) {
        float4 v = hx[c];
        x[c*4+0] = v.x; x[c*4+1] = v.y; x[c*4+2] = v.z; x[c*4+3] = v.w;
    }
    float* arow = acc + (size_t)node * 32;
#pragma unroll
    for (int jb = 0; jb < 8; ++jb) {
        float o[4];
#pragma unroll
        for (int q = 0; q < 4; ++q) {
            int j = jb * 4 + q;
            float a = b1[j];
#pragma unroll
            for (int i = 0; i < 32; ++i)
                a += x[i] * W1[j * 128 + i];
            o[q] = a;
        }
        *(float4*)(arow + jb * 4) = make_float4(o[0], o[1], o[2], o[3]);
    }
}

// ---------------------------------------------------------------------------
// acc(=out)[node] += hkk[node] @ W1blk.T  (row stride 128)
// ---------------------------------------------------------------------------
__global__ __launch_bounds__(256) void fold_w1(
    const float* __restrict__ hkk, const float* __restrict__ W1blk,
    float* __restrict__ acc, int n1)
{
    int node = blockIdx.x * 256 + threadIdx.x;
    if (node >= n1) return;
    float x[32];
    const float4* hx = (const float4*)(hkk + (size_t)node * 32);
#pragma unroll
    for (int c = 0; c < 8; ++c) {
        float4 v = hx[c];
        x[c*4+0] = v.x; x[c*4+1] = v.y; x[c*4+2] = v.z; x[c*4+3] = v.w;
    }
    float* arow = acc + (size_t)node * 32;
#pragma unroll
    for (int jb = 0; jb < 8; ++jb) {
        float4 cur = *(float4*)(arow + jb * 4);
        float o[4] = { cur.x, cur.y, cur.z, cur.w };
#pragma unroll
        for (int q = 0; q < 4; ++q) {
            int j = jb * 4 + q;
            float a = o[q];
#pragma unroll
            for (int i = 0; i < 32; ++i)
                a += x[i] * W1blk[j * 128 + i];
            o[q] = a;
        }
        *(float4*)(arow + jb * 4) = make_float4(o[0], o[1], o[2], o[3]);
    }
}

// ---------------------------------------------------------------------------
// out[node] = tanh(acc[node]) @ W2.T + b2   (in-place on out)
// ---------------------------------------------------------------------------
__global__ __launch_bounds__(256) void finish_out(
    float* __restrict__ acc, const float* __restrict__ W2,
    const float* __restrict__ b2, int n1)
{
    int node = blockIdx.x * 256 + threadIdx.x;
    if (node >= n1) return;
    float tv[32];
    const float4* ax = (const float4*)(acc + (size_t)node * 32);
#pragma unroll
    for (int c = 0; c < 8; ++c) {
        float4 v = ax[c];
        tv[c*4+0] = tanhf_(v.x); tv[c*4+1] = tanhf_(v.y);
        tv[c*4+2] = tanhf_(v.z); tv[c*4+3] = tanhf_(v.w);
    }
    float* orow = acc + (size_t)node * 32;
#pragma unroll
    for (int ob = 0; ob < 8; ++ob) {
        float o[4];
#pragma unroll
        for (int q = 0; q < 4; ++q) {
            int oj = ob * 4 + q;
            float a = b2[oj];
#pragma unroll
            for (int j = 0; j < 32; ++j)
                a += tv[j] * W2[oj * 32 + j];
            o[q] = a;
        }
        *(float4*)(orow + ob * 4) = make_float4(o[0], o[1], o[2], o[3]);
    }
}

// ---------------------------------------------------------------------------
// Fallback: atomic scatter (slow, correct; needs only n1*96*4 ws bytes)
// ---------------------------------------------------------------------------
template <int K>
__global__ __launch_bounds__(256) void gru_edges_atomic_noG(
    const int* __restrict__ idx, int nE,
    const float* __restrict__ h,
    const float* __restrict__ Wih, const float* __restrict__ bih,
    const float* __restrict__ Whh, const float* __restrict__ bhh,
    float* __restrict__ hk)
{
    int e = blockIdx.x * 256 + threadIdx.x;
    if (e >= nE) return;
    float hv[32];
#pragma unroll
    for (int t = 0; t < K; ++t) {
        int node = idx[(size_t)e * K + t];
        float x[32];
        const float4* hx = (const float4*)(h + (size_t)node * 32);
#pragma unroll
        for (int c = 0; c < 8; ++c) {
            float4 v = hx[c];
            x[c*4+0] = v.x; x[c*4+1] = v.y; x[c*4+2] = v.z; x[c*4+3] = v.w;
        }
        float hn_[32];
#pragma unroll
        for (int j = 0; j < 32; ++j) {
            float ir = bih[j], iz = bih[32 + j], in_ = bih[64 + j];
#pragma unroll
            for (int i = 0; i < 32; ++i) {
                ir  += x[i] * Wih[j * 32 + i];
                iz  += x[i] * Wih[(32 + j) * 32 + i];
                in_ += x[i] * Wih[(64 + j) * 32 + i];
            }
            float hr = bhh[j], hz = bhh[32 + j], hn2 = bhh[64 + j];
            if (t > 0) {
#pragma unroll
                for (int i = 0; i < 32; ++i) {
                    hr  += hv[i] * Whh[j * 32 + i];
                    hz  += hv[i] * Whh[(32 + j) * 32 + i];
                    hn2 += hv[i] * Whh[(64 + j) * 32 + i];
                }
            }
            float r = sigmoidf_(ir + hr);
            float z = sigmoidf_(iz + hz);
            float n = tanhf_(in_ + r * hn2);
            hn_[j] = (t > 0) ? ((1.0f - z) * n + z * hv[j]) : (1.0f - z) * n;
        }
        float* dst = hk + (size_t)node * 32;
#pragma unroll
        for (int j = 0; j < 32; ++j) {
            hv[j] = hn_[j];
            atomicAdd(dst + j, hn_[j]);
        }
    }
}

__global__ __launch_bounds__(256) void mlp_out_fb(
    const float* __restrict__ h, const float* __restrict__ hk, int n1,
    const float* __restrict__ W1, const float* __restrict__ b1,
    const float* __restrict__ W2, const float* __restrict__ b2,
    float* __restrict__ out)
{
    int node = blockIdx.x * 256 + threadIdx.x;
    if (node >= n1) return;
    float acc[32];
#pragma unroll
    for (int j = 0; j < 32; ++j) acc[j] = b1[j];
    const float* zsrc[4];
    zsrc[0] = h + (size_t)node * 32;
    zsrc[1] = hk + (size_t)node * 32;
    zsrc[2] = hk + (size_t)n1 * 32 + (size_t)node * 32;
    zsrc[3] = hk + (size_t)n1 * 64 + (size_t)node * 32;
#pragma unroll
    for (int m = 0; m < 4; ++m) {
        float zc[32];
        const float4* zp = (const float4*)zsrc[m];
#pragma unroll
        for (int c = 0; c < 8; ++c) {
            float4 v = zp[c];
            zc[c*4+0] = v.x; zc[c*4+1] = v.y; zc[c*4+2] = v.z; zc[c*4+3] = v.w;
        }
#pragma unroll
        for (int j = 0; j < 32; ++j) {
#pragma unroll
            for (int i = 0; i < 32; ++i)
                acc[j] += zc[i] * W1[j * 128 + m * 32 + i];
        }
    }
    float tv[32];
#pragma unroll
    for (int j = 0; j < 32; ++j) tv[j] = tanhf_(acc[j]);
    float* orow = out + (size_t)node * 32;
#pragma unroll
    for (int ob = 0; ob < 8; ++ob) {
        float o[4];
#pragma unroll
        for (int q = 0; q < 4; ++q) {
            int oj = ob * 4 + q;
            float a = b2[oj];
#pragma unroll
            for (int j = 0; j < 32; ++j)
                a += tv[j] * W2[oj * 32 + j];
            o[q] = a;
        }
        *(float4*)(orow + ob * 4) = make_float4(o[0], o[1], o[2], o[3]);
    }
}

// ---------------------------------------------------------------------------
static inline size_t alignUp(size_t x, size_t a) { return (x + a - 1) & ~(a - 1); }

extern "C" void kernel_launch(void* const* d_in, const int* in_sizes, int n_in,
                              void* d_out, int out_size, void* d_ws, size_t ws_size,
                              hipStream_t stream)
{
    const float* h    = (const float*)d_in[0];
    const int*   idx2 = (const int*)d_in[1];
    const int*   idx3 = (const int*)d_in[2];
    const int*   idx4 = (const int*)d_in[3];
    const float* Wih  = (const float*)d_in[4];
    const float* Whh  = (const float*)d_in[5];
    const float* bih  = (const float*)d_in[6];
    const float* bhh  = (const float*)d_in[7];
    const float* W1   = (const float*)d_in[8];
    const float* b1   = (const float*)d_in[9];
    const float* W2   = (const float*)d_in[10];
    const float* b2   = (const float*)d_in[11];
    float* out = (float*)d_out;

    int n1 = in_sizes[0] / 32;
    int n2 = in_sizes[1] / 2;
    int n3 = in_sizes[2] / 3;
    int n4 = in_sizes[3] / 4;
    int nEmax = n2 > n3 ? n2 : n3; if (n4 > nEmax) nEmax = n4;

    const int NCOL = 6;                       // k2:1 + k3:2 + k4:3 columns
    int M = NCOL * n1;                        // joint count/offs length
    int B0 = (M + 255) / 256;
    int B1 = (B0 + 255) / 256;
    size_t totE = (size_t)n2 + 2 * (size_t)n3 + 3 * (size_t)n4;

    // ---- workspace layout ----
    size_t off = 0;
    size_t h0Off  = off; off = alignUp(off + (size_t)n1 * 32 * 4, 256);
    size_t hsOff  = off; off = alignUp(off + (size_t)nEmax * 32 * 4, 256);
    size_t hkkOff = off; off = alignUp(off + (size_t)n1 * 32 * 4, 256);
    size_t cntOff = off; off = alignUp(off + (size_t)M * 4, 256);       // counts -> cursor
    size_t c0Off  = off; off = alignUp(off + (size_t)3 * n1 * 4, 256);  // cnt0 (3 k's)
    size_t oOff   = off; off = alignUp(off + (size_t)M * 4, 256);       // incl0 -> offs
    size_t entOff = off; off = alignUp(off + totE * 4, 256);
    size_t b0Off  = off; off = alignUp(off + (size_t)B0 * 4, 256);
    size_t i1Off  = off; off = alignUp(off + (size_t)B0 * 4, 256);
    size_t b1Off  = off; off = alignUp(off + (size_t)B1 * 4, 256);
    size_t need = off;

    int blocksN1 = (n1 + 255) / 256;
    char* ws = (char*)d_ws;

    if (ws_size >= need && B1 <= 1024) {
        float* h0     = (float*)(ws + h0Off);
        float* hstate = (float*)(ws + hsOff);
        float* hkk    = (float*)(ws + hkkOff);
        int*   counts = (int*)(ws + cntOff);   // later: cursor
        int*   cnt0   = (int*)(ws + c0Off);
        int*   offs   = (int*)(ws + oOff);     // incl0 -> finalize in place
        int*   ent    = (int*)(ws + entOff);
        int*   bsums0 = (int*)(ws + b0Off);
        int*   incl1  = (int*)(ws + i1Off);
        int*   bsums1 = (int*)(ws + b1Off);

        // --- CSR build (batched, joint scan over 6 columns) ---
        hipMemsetAsync(counts, 0, ((size_t)M + 3 * n1) * 4, stream); // counts+cnt0 adjacent
        hist_all<2><<<(n2 * 2 + 255) / 256, 256, 0, stream>>>(idx2, n2 * 2, cnt0,          counts,          n1);
        hist_all<3><<<(n3 * 3 + 255) / 256, 256, 0, stream>>>(idx3, n3 * 3, cnt0 + n1,     counts + n1,     n1);
        hist_all<4><<<(n4 * 4 + 255) / 256, 256, 0, stream>>>(idx4, n4 * 4, cnt0 + 2 * n1, counts + 3 * n1, n1);
        scan_block<<<B0, 256, 0, stream>>>(counts, offs, bsums0, M);
        scan_block<<<B1, 256, 0, stream>>>(bsums0, incl1, bsums1, B0);
        scan_bsums<<<1, 1024, 0, stream>>>(bsums1, B1);
        finalize_joint<<<B0, 256, 0, stream>>>(offs, counts, bsums0, incl1, bsums1, M);
        hipMemcpyAsync(counts, offs, (size_t)M * 4, hipMemcpyDeviceToDevice, stream); // cursor = offs
        fill_all<2><<<(n2 * 1 + 255) / 256, 256, 0, stream>>>(idx2, n2 * 1, counts,          ent, n1);
        fill_all<3><<<(n3 * 2 + 255) / 256, 256, 0, stream>>>(idx3, n3 * 2, counts + n1,     ent, n1);
        fill_all<4><<<(n4 * 3 + 255) / 256, 256, 0, stream>>>(idx4, n4 * 3, counts + 3 * n1, ent, n1);

        // --- node-side precomputes ---
        compute_h0<<<blocksN1, 256, 0, stream>>>(h, Wih, bih, bhh, h0, n1);
        init_acc<<<blocksN1, 256, 0, stream>>>(h, W1, b1, out, n1);

        // --- per-k pipeline ---
        const int* idxs[3] = { idx2, idx3, idx4 };
        int nEs[3] = { n2, n3, n4 };
        int colbase[3] = { 0, 1, 3 };
        int gaBlocks = ((n1 * 8) + 255) / 256;

        for (int kk = 0; kk < 3; ++kk) {
            const int* idx = idxs[kk];
            int nE = nEs[kk];
            int blocksE = (nE + 255) / 256;

            init_hkk<<<gaBlocks, 256, 0, stream>>>(cnt0 + kk * n1, h0, hkk, n1);

            int K = kk + 2;
            for (int t = 1; t < K; ++t) {
                if (K == 2)      gru_step_h<2, 1><<<blocksE, 256, 0, stream>>>(idx, nE, h, h0, Wih, bih, Whh, bhh, hstate);
                else if (K == 3) {
                    if (t == 1)  gru_step_h<3, 1><<<blocksE, 256, 0, stream>>>(idx, nE, h, h0, Wih, bih, Whh, bhh, hstate);
                    else         gru_step_h<3, 2><<<blocksE, 256, 0, stream>>>(idx, nE, h, h0, Wih, bih, Whh, bhh, hstate);
                } else {
                    if (t == 1)      gru_step_h<4, 1><<<blocksE, 256, 0, stream>>>(idx, nE, h, h0, Wih, bih, Whh, bhh, hstate);
                    else if (t == 2) gru_step_h<4, 2><<<blocksE, 256, 0, stream>>>(idx, nE, h, h0, Wih, bih, Whh, bhh, hstate);
                    else             gru_step_h<4, 3><<<blocksE, 256, 0, stream>>>(idx, nE, h, h0, Wih, bih, Whh, bhh, hstate);
                }
                int col = colbase[kk] + (t - 1);
                gather_add<<<gaBlocks, 256, 0, stream>>>(
                    offs + (size_t)col * n1, counts + (size_t)col * n1,
                    ent, hstate, hkk, n1);
            }

            fold_w1<<<blocksN1, 256, 0, stream>>>(hkk, W1 + (kk + 1) * 32, out, n1);
        }

        finish_out<<<blocksN1, 256, 0, stream>>>(out, W2, b2, n1);
        return;
    }

    // ===== fallback: atomic path, hk only (n1*96*4 bytes) =====
    float* hk = (float*)d_ws;
    hipMemsetAsync(d_ws, 0, (size_t)n1 * 96 * 4, stream);
    gru_edges_atomic_noG<2><<<(n2 + 255) / 256, 256, 0, stream>>>(
        idx2, n2, h, Wih, bih, Whh, bhh, hk);
    gru_edges_atomic_noG<3><<<(n3 + 255) / 256, 256, 0, stream>>>(
        idx3, n3, h, Wih, bih, Whh, bhh, hk + (size_t)n1 * 32);
    gru_edges_atomic_noG<4><<<(n4 + 255) / 256, 256, 0, stream>>>(
        idx4, n4, h, Wih, bih, Whh, bhh, hk + (size_t)n1 * 64);
    mlp_out_fb<<<blocksN1, 256, 0, stream>>>(h, hk, n1, W1, b1, W2, b2, out);
}

// Round 8
// 2302.146 us; speedup vs baseline: 1.2816x; 1.2816x over previous
//
#include <hip/hip_runtime.h>
#include <hip/hip_bf16.h>

__device__ __forceinline__ float sigmoidf_(float x) {
    return 1.0f / (1.0f + __expf(-x));
}
__device__ __forceinline__ float tanhf_(float x) {
    float e = __expf(2.0f * x);
    return 1.0f - 2.0f / (e + 1.0f);
}

// ---------------------------------------------------------------------------
// h0[node] = GRU step with hprev=0 (gh = bhh). Wih staged in LDS.
// ---------------------------------------------------------------------------
__global__ __launch_bounds__(256) void compute_h0(
    const float* __restrict__ h, const float* __restrict__ Wih,
    const float* __restrict__ bih, const float* __restrict__ bhh,
    float* __restrict__ h0, int n1)
{
    __shared__ float sW[3072];
    __shared__ float sB[192];
    {
        const float4* a4 = (const float4*)Wih;
        float4* sa = (float4*)sW;
#pragma unroll
        for (int c = 0; c < 3; ++c)
            sa[c * 256 + threadIdx.x] = a4[c * 256 + threadIdx.x];
        if (threadIdx.x < 192)
            sB[threadIdx.x] = (threadIdx.x < 96) ? bih[threadIdx.x]
                                                 : bhh[threadIdx.x - 96];
    }
    __syncthreads();

    int node = blockIdx.x * 256 + threadIdx.x;
    if (node >= n1) return;
    float x[32];
    const float4* hx = (const float4*)(h + (size_t)node * 32);
#pragma unroll
    for (int c = 0; c < 8; ++c) {
        float4 v = hx[c];
        x[c*4+0] = v.x; x[c*4+1] = v.y; x[c*4+2] = v.z; x[c*4+3] = v.w;
    }
    float o[32];
#pragma unroll
    for (int j = 0; j < 32; ++j) {
        float ir = sB[j], iz = sB[32 + j], in_ = sB[64 + j];
        const float4* wr = (const float4*)(sW + j * 32);
        const float4* wz = (const float4*)(sW + (32 + j) * 32);
        const float4* wn = (const float4*)(sW + (64 + j) * 32);
#pragma unroll
        for (int c = 0; c < 8; ++c) {
            float4 a = wr[c], b = wz[c], d = wn[c];
            ir  += x[c*4+0]*a.x + x[c*4+1]*a.y + x[c*4+2]*a.z + x[c*4+3]*a.w;
            iz  += x[c*4+0]*b.x + x[c*4+1]*b.y + x[c*4+2]*b.z + x[c*4+3]*b.w;
            in_ += x[c*4+0]*d.x + x[c*4+1]*d.y + x[c*4+2]*d.z + x[c*4+3]*d.w;
        }
        float r = sigmoidf_(ir + sB[96 + j]);
        float z = sigmoidf_(iz + sB[128 + j]);
        float n = tanhf_(in_ + r * sB[160 + j]);
        o[j] = (1.0f - z) * n;
    }
    float4* dst = (float4*)(h0 + (size_t)node * 32);
#pragma unroll
    for (int c = 0; c < 8; ++c)
        dst[c] = make_float4(o[c*4+0], o[c*4+1], o[c*4+2], o[c*4+3]);
}

// ---------------------------------------------------------------------------
// Batched histogram per k-list: col 0 -> cnt0, cols t>=1 -> counts[(t-1)*n1+]
// ---------------------------------------------------------------------------
template <int K>
__global__ __launch_bounds__(256) void hist_all(
    const int* __restrict__ idx, int nI, int* __restrict__ cnt0,
    int* __restrict__ counts, int n1)
{
    int i = blockIdx.x * 256 + threadIdx.x;
    if (i >= nI) return;
    int t = i % K;
    int node = idx[i];
    if (t == 0) atomicAdd(&cnt0[node], 1);
    else        atomicAdd(&counts[(size_t)(t - 1) * n1 + node], 1);
}

// ---------------------------------------------------------------------------
// Scan machinery (3-level)
// ---------------------------------------------------------------------------
__global__ __launch_bounds__(256) void scan_block(
    const int* __restrict__ in, int* __restrict__ incl,
    int* __restrict__ bsums, int n)
{
    __shared__ int s[256];
    int i = blockIdx.x * 256 + threadIdx.x;
    int v = (i < n) ? in[i] : 0;
    s[threadIdx.x] = v;
    __syncthreads();
    for (int d = 1; d < 256; d <<= 1) {
        int tt = (threadIdx.x >= d) ? s[threadIdx.x - d] : 0;
        __syncthreads();
        s[threadIdx.x] += tt;
        __syncthreads();
    }
    if (i < n) incl[i] = s[threadIdx.x];
    if (threadIdx.x == 255) bsums[blockIdx.x] = s[255];
}

__global__ __launch_bounds__(1024) void scan_bsums(int* bsums, int nb)
{
    __shared__ int s[1024];
    int v = (threadIdx.x < nb) ? bsums[threadIdx.x] : 0;
    s[threadIdx.x] = v;
    __syncthreads();
    for (int d = 1; d < 1024; d <<= 1) {
        int tt = (threadIdx.x >= d) ? s[threadIdx.x - d] : 0;
        __syncthreads();
        s[threadIdx.x] += tt;
        __syncthreads();
    }
    if (threadIdx.x < nb) bsums[threadIdx.x] = s[threadIdx.x] - v; // exclusive
}

// offs[i] (in-place over incl0) = global EXCLUSIVE prefix of counts
__global__ __launch_bounds__(256) void finalize_joint(
    int* __restrict__ offs, const int* __restrict__ counts,
    const int* __restrict__ bsums0, const int* __restrict__ incl1,
    const int* __restrict__ bsums1ex, int M)
{
    int i = blockIdx.x * 256 + threadIdx.x;
    if (i >= M) return;
    int b0 = i >> 8, b1 = b0 >> 8;
    offs[i] = offs[i] - counts[i] + (incl1[b0] - bsums0[b0]) + bsums1ex[b1];
}

// ---------------------------------------------------------------------------
// Batched ticket fill for columns t>=1 of a k-list
// ---------------------------------------------------------------------------
template <int K>
__global__ __launch_bounds__(256) void fill_all(
    const int* __restrict__ idx, int nW,   // nW = nE*(K-1)
    int* __restrict__ cursor, int* __restrict__ ent, int n1)
{
    int i = blockIdx.x * 256 + threadIdx.x;
    if (i >= nW) return;
    int e = i / (K - 1), tt = i % (K - 1);
    int node = idx[(size_t)e * K + tt + 1];
    int p = atomicAdd(&cursor[(size_t)tt * n1 + node], 1);
    ent[p] = e;
}

// ---------------------------------------------------------------------------
// One GRU step (t = T >= 1). x gathered from h; hv from h0 (T==1) or hstate.
// Wih+Whh+biases staged in LDS (broadcast reads, conflict-free).
// ---------------------------------------------------------------------------
template <int K, int T>
__global__ __launch_bounds__(256) void gru_step_h(
    const int* __restrict__ idx, int nE,
    const float* __restrict__ h, const float* __restrict__ h0,
    const float* __restrict__ Wih, const float* __restrict__ bih,
    const float* __restrict__ Whh, const float* __restrict__ bhh,
    float* __restrict__ hstate)
{
    __shared__ float sWih[3072];
    __shared__ float sWhh[3072];
    __shared__ float sB[192];
    {
        const float4* a4 = (const float4*)Wih;
        const float4* b4 = (const float4*)Whh;
        float4* sa = (float4*)sWih;
        float4* sb = (float4*)sWhh;
#pragma unroll
        for (int c = 0; c < 3; ++c) {
            sa[c * 256 + threadIdx.x] = a4[c * 256 + threadIdx.x];
            sb[c * 256 + threadIdx.x] = b4[c * 256 + threadIdx.x];
        }
        if (threadIdx.x < 192)
            sB[threadIdx.x] = (threadIdx.x < 96) ? bih[threadIdx.x]
                                                 : bhh[threadIdx.x - 96];
    }
    __syncthreads();

    int e = blockIdx.x * 256 + threadIdx.x;
    if (e >= nE) return;

    float hv[32];
    if (T == 1) {
        int np = idx[(size_t)e * K];
        const float4* hp = (const float4*)(h0 + (size_t)np * 32);
#pragma unroll
        for (int c = 0; c < 8; ++c) {
            float4 v = hp[c];
            hv[c*4+0] = v.x; hv[c*4+1] = v.y; hv[c*4+2] = v.z; hv[c*4+3] = v.w;
        }
    } else {
        const float4* hp = (const float4*)(hstate + (size_t)e * 32);
#pragma unroll
        for (int c = 0; c < 8; ++c) {
            float4 v = hp[c];
            hv[c*4+0] = v.x; hv[c*4+1] = v.y; hv[c*4+2] = v.z; hv[c*4+3] = v.w;
        }
    }

    int node = idx[(size_t)e * K + T];
    float x[32];
    {
        const float4* hx = (const float4*)(h + (size_t)node * 32);
#pragma unroll
        for (int c = 0; c < 8; ++c) {
            float4 v = hx[c];
            x[c*4+0] = v.x; x[c*4+1] = v.y; x[c*4+2] = v.z; x[c*4+3] = v.w;
        }
    }

    float hn[32];
#pragma unroll
    for (int j = 0; j < 32; ++j) {
        float ir = sB[j], iz = sB[32 + j], in_ = sB[64 + j];
        float hr = sB[96 + j], hz = sB[128 + j], hn2 = sB[160 + j];
        const float4* ir4 = (const float4*)(sWih + j * 32);
        const float4* iz4 = (const float4*)(sWih + (32 + j) * 32);
        const float4* in4 = (const float4*)(sWih + (64 + j) * 32);
        const float4* hr4 = (const float4*)(sWhh + j * 32);
        const float4* hz4 = (const float4*)(sWhh + (32 + j) * 32);
        const float4* hn4 = (const float4*)(sWhh + (64 + j) * 32);
#pragma unroll
        for (int c = 0; c < 8; ++c) {
            float4 wa = ir4[c], wb = iz4[c], wc = in4[c];
            float4 va = hr4[c], vb = hz4[c], vc = hn4[c];
            float x0 = x[c*4+0], x1 = x[c*4+1], x2 = x[c*4+2], x3 = x[c*4+3];
            float h0_ = hv[c*4+0], h1 = hv[c*4+1], h2 = hv[c*4+2], h3 = hv[c*4+3];
            ir  += x0*wa.x + x1*wa.y + x2*wa.z + x3*wa.w;
            iz  += x0*wb.x + x1*wb.y + x2*wb.z + x3*wb.w;
            in_ += x0*wc.x + x1*wc.y + x2*wc.z + x3*wc.w;
            hr  += h0_*va.x + h1*va.y + h2*va.z + h3*va.w;
            hz  += h0_*vb.x + h1*vb.y + h2*vb.z + h3*vb.w;
            hn2 += h0_*vc.x + h1*vc.y + h2*vc.z + h3*vc.w;
        }
        float r = sigmoidf_(ir + hr);
        float z = sigmoidf_(iz + hz);
        float n = tanhf_(in_ + r * hn2);
        hn[j] = (1.0f - z) * n + z * hv[j];
    }
    float4* hs = (float4*)(hstate + (size_t)e * 32);
#pragma unroll
    for (int c = 0; c < 8; ++c)
        hs[c] = make_float4(hn[c*4+0], hn[c*4+1], hn[c*4+2], hn[c*4+3]);
}

// ---------------------------------------------------------------------------
// hkk[node] = cnt0[node] * h0[node]
// ---------------------------------------------------------------------------
__global__ __launch_bounds__(256) void init_hkk(
    const int* __restrict__ cnt0, const float* __restrict__ h0,
    float* __restrict__ hkk, int n1)
{
    int gid = blockIdx.x * 256 + threadIdx.x;
    int node = gid >> 3;
    int sub = gid & 7;
    if (node >= n1) return;
    float c = (float)cnt0[node];
    float4 v = *(const float4*)(h0 + (size_t)node * 32 + sub * 4);
    v.x *= c; v.y *= c; v.z *= c; v.w *= c;
    *(float4*)(hkk + (size_t)node * 32 + sub * 4) = v;
}

// ---------------------------------------------------------------------------
// hkk[node] += sum over entries of hstate rows. 8 threads/node, no atomics.
// ---------------------------------------------------------------------------
__global__ __launch_bounds__(256) void gather_add(
    const int* __restrict__ offs, const int* __restrict__ endp,
    const int* __restrict__ ent,
    const float* __restrict__ hstate, float* __restrict__ hkk, int n1)
{
    int gid = blockIdx.x * 256 + threadIdx.x;
    int node = gid >> 3;
    int sub = gid & 7;
    if (node >= n1) return;
    int beg = offs[node], end = endp[node];
    if (beg == end) return;
    float4 a = make_float4(0.f, 0.f, 0.f, 0.f);
    for (int p = beg; p < end; ++p) {
        int e = ent[p];
        float4 v = *(const float4*)(hstate + (size_t)e * 32 + sub * 4);
        a.x += v.x; a.y += v.y; a.z += v.z; a.w += v.w;
    }
    float* dst = hkk + (size_t)node * 32 + sub * 4;
    float4 cur = *(float4*)dst;
    cur.x += a.x; cur.y += a.y; cur.z += a.z; cur.w += a.w;
    *(float4*)dst = cur;
}

// ---------------------------------------------------------------------------
// acc(=out)[node] = b1 + h[node] @ W1[:,0:32].T   (W1 block 0 staged in LDS)
// ---------------------------------------------------------------------------
__global__ __launch_bounds__(256) void init_acc(
    const float* __restrict__ h, const float* __restrict__ W1,
    const float* __restrict__ b1, float* __restrict__ acc, int n1)
{
    __shared__ float sW[1024];
#pragma unroll
    for (int c = 0; c < 4; ++c) {
        int i = c * 256 + threadIdx.x;
        sW[i] = W1[(i >> 5) * 128 + (i & 31)];
    }
    __syncthreads();

    int node = blockIdx.x * 256 + threadIdx.x;
    if (node >= n1) return;
    float x[32];
    const float4* hx = (const float4*)(h + (size_t)node * 32);
#pragma unroll
    for (int c = 0; c < 8; ++c) {
        float4 v = hx[c];
        x[c*4+0] = v.x; x[c*4+1] = v.y; x[c*4+2] = v.z; x[c*4+3] = v.w;
    }
    float* arow = acc + (size_t)node * 32;
#pragma unroll
    for (int jb = 0; jb < 8; ++jb) {
        float o[4];
#pragma unroll
        for (int q = 0; q < 4; ++q) {
            int j = jb * 4 + q;
            float a = b1[j];
            const float4* w4 = (const float4*)(sW + j * 32);
#pragma unroll
            for (int c = 0; c < 8; ++c) {
                float4 w = w4[c];
                a += x[c*4+0]*w.x + x[c*4+1]*w.y + x[c*4+2]*w.z + x[c*4+3]*w.w;
            }
            o[q] = a;
        }
        *(float4*)(arow + jb * 4) = make_float4(o[0], o[1], o[2], o[3]);
    }
}

// ---------------------------------------------------------------------------
// acc(=out)[node] += hkk[node] @ W1blk.T  (block staged in LDS)
// ---------------------------------------------------------------------------
__global__ __launch_bounds__(256) void fold_w1(
    const float* __restrict__ hkk, const float* __restrict__ W1blk,
    float* __restrict__ acc, int n1)
{
    __shared__ float sW[1024];
#pragma unroll
    for (int c = 0; c < 4; ++c) {
        int i = c * 256 + threadIdx.x;
        sW[i] = W1blk[(i >> 5) * 128 + (i & 31)];
    }
    __syncthreads();

    int node = blockIdx.x * 256 + threadIdx.x;
    if (node >= n1) return;
    float x[32];
    const float4* hx = (const float4*)(hkk + (size_t)node * 32);
#pragma unroll
    for (int c = 0; c < 8; ++c) {
        float4 v = hx[c];
        x[c*4+0] = v.x; x[c*4+1] = v.y; x[c*4+2] = v.z; x[c*4+3] = v.w;
    }
    float* arow = acc + (size_t)node * 32;
#pragma unroll
    for (int jb = 0; jb < 8; ++jb) {
        float4 cur = *(float4*)(arow + jb * 4);
        float o[4] = { cur.x, cur.y, cur.z, cur.w };
#pragma unroll
        for (int q = 0; q < 4; ++q) {
            int j = jb * 4 + q;
            float a = o[q];
            const float4* w4 = (const float4*)(sW + j * 32);
#pragma unroll
            for (int c = 0; c < 8; ++c) {
                float4 w = w4[c];
                a += x[c*4+0]*w.x + x[c*4+1]*w.y + x[c*4+2]*w.z + x[c*4+3]*w.w;
            }
            o[q] = a;
        }
        *(float4*)(arow + jb * 4) = make_float4(o[0], o[1], o[2], o[3]);
    }
}

// ---------------------------------------------------------------------------
// out[node] = tanh(acc[node]) @ W2.T + b2   (in-place; W2 staged in LDS)
// ---------------------------------------------------------------------------
__global__ __launch_bounds__(256) void finish_out(
    float* __restrict__ acc, const float* __restrict__ W2,
    const float* __restrict__ b2, int n1)
{
    __shared__ float sW[1024];
    {
        const float4* w4 = (const float4*)W2;
        float4* s4 = (float4*)sW;
        if (threadIdx.x < 256) s4[threadIdx.x] = w4[threadIdx.x];
    }
    __syncthreads();

    int node = blockIdx.x * 256 + threadIdx.x;
    if (node >= n1) return;
    float tv[32];
    const float4* ax = (const float4*)(acc + (size_t)node * 32);
#pragma unroll
    for (int c = 0; c < 8; ++c) {
        float4 v = ax[c];
        tv[c*4+0] = tanhf_(v.x); tv[c*4+1] = tanhf_(v.y);
        tv[c*4+2] = tanhf_(v.z); tv[c*4+3] = tanhf_(v.w);
    }
    float* orow = acc + (size_t)node * 32;
#pragma unroll
    for (int ob = 0; ob < 8; ++ob) {
        float o[4];
#pragma unroll
        for (int q = 0; q < 4; ++q) {
            int oj = ob * 4 + q;
            float a = b2[oj];
            const float4* w4 = (const float4*)(sW + oj * 32);
#pragma unroll
            for (int c = 0; c < 8; ++c) {
                float4 w = w4[c];
                a += tv[c*4+0]*w.x + tv[c*4+1]*w.y + tv[c*4+2]*w.z + tv[c*4+3]*w.w;
            }
            o[q] = a;
        }
        *(float4*)(orow + ob * 4) = make_float4(o[0], o[1], o[2], o[3]);
    }
}

// ---------------------------------------------------------------------------
// Fallback: atomic scatter (slow, correct; needs only n1*96*4 ws bytes)
// ---------------------------------------------------------------------------
template <int K>
__global__ __launch_bounds__(256) void gru_edges_atomic_noG(
    const int* __restrict__ idx, int nE,
    const float* __restrict__ h,
    const float* __restrict__ Wih, const float* __restrict__ bih,
    const float* __restrict__ Whh, const float* __restrict__ bhh,
    float* __restrict__ hk)
{
    int e = blockIdx.x * 256 + threadIdx.x;
    if (e >= nE) return;
    float hv[32];
#pragma unroll
    for (int t = 0; t < K; ++t) {
        int node = idx[(size_t)e * K + t];
        float x[32];
        const float4* hx = (const float4*)(h + (size_t)node * 32);
#pragma unroll
        for (int c = 0; c < 8; ++c) {
            float4 v = hx[c];
            x[c*4+0] = v.x; x[c*4+1] = v.y; x[c*4+2] = v.z; x[c*4+3] = v.w;
        }
        float hn_[32];
#pragma unroll
        for (int j = 0; j < 32; ++j) {
            float ir = bih[j], iz = bih[32 + j], in_ = bih[64 + j];
#pragma unroll
            for (int i = 0; i < 32; ++i) {
                ir  += x[i] * Wih[j * 32 + i];
                iz  += x[i] * Wih[(32 + j) * 32 + i];
                in_ += x[i] * Wih[(64 + j) * 32 + i];
            }
            float hr = bhh[j], hz = bhh[32 + j], hn2 = bhh[64 + j];
            if (t > 0) {
#pragma unroll
                for (int i = 0; i < 32; ++i) {
                    hr  += hv[i] * Whh[j * 32 + i];
                    hz  += hv[i] * Whh[(32 + j) * 32 + i];
                    hn2 += hv[i] * Whh[(64 + j) * 32 + i];
                }
            }
            float r = sigmoidf_(ir + hr);
            float z = sigmoidf_(iz + hz);
            float n = tanhf_(in_ + r * hn2);
            hn_[j] = (t > 0) ? ((1.0f - z) * n + z * hv[j]) : (1.0f - z) * n;
        }
        float* dst = hk + (size_t)node * 32;
#pragma unroll
        for (int j = 0; j < 32; ++j) {
            hv[j] = hn_[j];
            atomicAdd(dst + j, hn_[j]);
        }
    }
}

__global__ __launch_bounds__(256) void mlp_out_fb(
    const float* __restrict__ h, const float* __restrict__ hk, int n1,
    const float* __restrict__ W1, const float* __restrict__ b1,
    const float* __restrict__ W2, const float* __restrict__ b2,
    float* __restrict__ out)
{
    int node = blockIdx.x * 256 + threadIdx.x;
    if (node >= n1) return;
    float acc[32];
#pragma unroll
    for (int j = 0; j < 32; ++j) acc[j] = b1[j];
    const float* zsrc[4];
    zsrc[0] = h + (size_t)node * 32;
    zsrc[1] = hk + (size_t)node * 32;
    zsrc[2] = hk + (size_t)n1 * 32 + (size_t)node * 32;
    zsrc[3] = hk + (size_t)n1 * 64 + (size_t)node * 32;
#pragma unroll
    for (int m = 0; m < 4; ++m) {
        float zc[32];
        const float4* zp = (const float4*)zsrc[m];
#pragma unroll
        for (int c = 0; c < 8; ++c) {
            float4 v = zp[c];
            zc[c*4+0] = v.x; zc[c*4+1] = v.y; zc[c*4+2] = v.z; zc[c*4+3] = v.w;
        }
#pragma unroll
        for (int j = 0; j < 32; ++j) {
#pragma unroll
            for (int i = 0; i < 32; ++i)
                acc[j] += zc[i] * W1[j * 128 + m * 32 + i];
        }
    }
    float tv[32];
#pragma unroll
    for (int j = 0; j < 32; ++j) tv[j] = tanhf_(acc[j]);
    float* orow = out + (size_t)node * 32;
#pragma unroll
    for (int ob = 0; ob < 8; ++ob) {
        float o[4];
#pragma unroll
        for (int q = 0; q < 4; ++q) {
            int oj = ob * 4 + q;
            float a = b2[oj];
#pragma unroll
            for (int j = 0; j < 32; ++j)
                a += tv[j] * W2[oj * 32 + j];
            o[q] = a;
        }
        *(float4*)(orow + ob * 4) = make_float4(o[0], o[1], o[2], o[3]);
    }
}

// ---------------------------------------------------------------------------
static inline size_t alignUp(size_t x, size_t a) { return (x + a - 1) & ~(a - 1); }

extern "C" void kernel_launch(void* const* d_in, const int* in_sizes, int n_in,
                              void* d_out, int out_size, void* d_ws, size_t ws_size,
                              hipStream_t stream)
{
    const float* h    = (const float*)d_in[0];
    const int*   idx2 = (const int*)d_in[1];
    const int*   idx3 = (const int*)d_in[2];
    const int*   idx4 = (const int*)d_in[3];
    const float* Wih  = (const float*)d_in[4];
    const float* Whh  = (const float*)d_in[5];
    const float* bih  = (const float*)d_in[6];
    const float* bhh  = (const float*)d_in[7];
    const float* W1   = (const float*)d_in[8];
    const float* b1   = (const float*)d_in[9];
    const float* W2   = (const float*)d_in[10];
    const float* b2   = (const float*)d_in[11];
    float* out = (float*)d_out;

    int n1 = in_sizes[0] / 32;
    int n2 = in_sizes[1] / 2;
    int n3 = in_sizes[2] / 3;
    int n4 = in_sizes[3] / 4;
    int nEmax = n2 > n3 ? n2 : n3; if (n4 > nEmax) nEmax = n4;

    const int NCOL = 6;                       // k2:1 + k3:2 + k4:3 columns
    int M = NCOL * n1;                        // joint count/offs length
    int B0 = (M + 255) / 256;
    int B1 = (B0 + 255) / 256;
    size_t totE = (size_t)n2 + 2 * (size_t)n3 + 3 * (size_t)n4;

    // ---- workspace layout ----
    size_t off = 0;
    size_t h0Off  = off; off = alignUp(off + (size_t)n1 * 32 * 4, 256);
    size_t hsOff  = off; off = alignUp(off + (size_t)nEmax * 32 * 4, 256);
    size_t hkkOff = off; off = alignUp(off + (size_t)n1 * 32 * 4, 256);
    size_t cntOff = off; off = alignUp(off + (size_t)M * 4, 256);       // counts -> cursor
    size_t c0Off  = off; off = alignUp(off + (size_t)3 * n1 * 4, 256);  // cnt0 (3 k's)
    size_t oOff   = off; off = alignUp(off + (size_t)M * 4, 256);       // incl0 -> offs
    size_t entOff = off; off = alignUp(off + totE * 4, 256);
    size_t b0Off  = off; off = alignUp(off + (size_t)B0 * 4, 256);
    size_t i1Off  = off; off = alignUp(off + (size_t)B0 * 4, 256);
    size_t b1Off  = off; off = alignUp(off + (size_t)B1 * 4, 256);
    size_t need = off;

    int blocksN1 = (n1 + 255) / 256;
    char* ws = (char*)d_ws;

    if (ws_size >= need && B1 <= 1024) {
        float* h0     = (float*)(ws + h0Off);
        float* hstate = (float*)(ws + hsOff);
        float* hkk    = (float*)(ws + hkkOff);
        int*   counts = (int*)(ws + cntOff);   // later: cursor
        int*   cnt0   = (int*)(ws + c0Off);
        int*   offs   = (int*)(ws + oOff);     // incl0 -> finalize in place
        int*   ent    = (int*)(ws + entOff);
        int*   bsums0 = (int*)(ws + b0Off);
        int*   incl1  = (int*)(ws + i1Off);
        int*   bsums1 = (int*)(ws + b1Off);

        // --- CSR build (batched, joint scan over 6 columns) ---
        hipMemsetAsync(counts, 0, ((size_t)M + 3 * n1) * 4, stream); // counts+cnt0 adjacent
        hist_all<2><<<(n2 * 2 + 255) / 256, 256, 0, stream>>>(idx2, n2 * 2, cnt0,          counts,          n1);
        hist_all<3><<<(n3 * 3 + 255) / 256, 256, 0, stream>>>(idx3, n3 * 3, cnt0 + n1,     counts + n1,     n1);
        hist_all<4><<<(n4 * 4 + 255) / 256, 256, 0, stream>>>(idx4, n4 * 4, cnt0 + 2 * n1, counts + 3 * n1, n1);
        scan_block<<<B0, 256, 0, stream>>>(counts, offs, bsums0, M);
        scan_block<<<B1, 256, 0, stream>>>(bsums0, incl1, bsums1, B0);
        scan_bsums<<<1, 1024, 0, stream>>>(bsums1, B1);
        finalize_joint<<<B0, 256, 0, stream>>>(offs, counts, bsums0, incl1, bsums1, M);
        hipMemcpyAsync(counts, offs, (size_t)M * 4, hipMemcpyDeviceToDevice, stream); // cursor = offs
        fill_all<2><<<(n2 * 1 + 255) / 256, 256, 0, stream>>>(idx2, n2 * 1, counts,          ent, n1);
        fill_all<3><<<(n3 * 2 + 255) / 256, 256, 0, stream>>>(idx3, n3 * 2, counts + n1,     ent, n1);
        fill_all<4><<<(n4 * 3 + 255) / 256, 256, 0, stream>>>(idx4, n4 * 3, counts + 3 * n1, ent, n1);

        // --- node-side precomputes ---
        compute_h0<<<blocksN1, 256, 0, stream>>>(h, Wih, bih, bhh, h0, n1);
        init_acc<<<blocksN1, 256, 0, stream>>>(h, W1, b1, out, n1);

        // --- per-k pipeline ---
        const int* idxs[3] = { idx2, idx3, idx4 };
        int nEs[3] = { n2, n3, n4 };
        int colbase[3] = { 0, 1, 3 };
        int gaBlocks = ((n1 * 8) + 255) / 256;

        for (int kk = 0; kk < 3; ++kk) {
            const int* idx = idxs[kk];
            int nE = nEs[kk];
            int blocksE = (nE + 255) / 256;

            init_hkk<<<gaBlocks, 256, 0, stream>>>(cnt0 + kk * n1, h0, hkk, n1);

            int K = kk + 2;
            for (int t = 1; t < K; ++t) {
                if (K == 2)      gru_step_h<2, 1><<<blocksE, 256, 0, stream>>>(idx, nE, h, h0, Wih, bih, Whh, bhh, hstate);
                else if (K == 3) {
                    if (t == 1)  gru_step_h<3, 1><<<blocksE, 256, 0, stream>>>(idx, nE, h, h0, Wih, bih, Whh, bhh, hstate);
                    else         gru_step_h<3, 2><<<blocksE, 256, 0, stream>>>(idx, nE, h, h0, Wih, bih, Whh, bhh, hstate);
                } else {
                    if (t == 1)      gru_step_h<4, 1><<<blocksE, 256, 0, stream>>>(idx, nE, h, h0, Wih, bih, Whh, bhh, hstate);
                    else if (t == 2) gru_step_h<4, 2><<<blocksE, 256, 0, stream>>>(idx, nE, h, h0, Wih, bih, Whh, bhh, hstate);
                    else             gru_step_h<4, 3><<<blocksE, 256, 0, stream>>>(idx, nE, h, h0, Wih, bih, Whh, bhh, hstate);
                }
                int col = colbase[kk] + (t - 1);
                gather_add<<<gaBlocks, 256, 0, stream>>>(
                    offs + (size_t)col * n1, counts + (size_t)col * n1,
                    ent, hstate, hkk, n1);
            }

            fold_w1<<<blocksN1, 256, 0, stream>>>(hkk, W1 + (kk + 1) * 32, out, n1);
        }

        finish_out<<<blocksN1, 256, 0, stream>>>(out, W2, b2, n1);
        return;
    }

    // ===== fallback: atomic path, hk only (n1*96*4 bytes) =====
    float* hk = (float*)d_ws;
    hipMemsetAsync(d_ws, 0, (size_t)n1 * 96 * 4, stream);
    gru_edges_atomic_noG<2><<<(n2 + 255) / 256, 256, 0, stream>>>(
        idx2, n2, h, Wih, bih, Whh, bhh, hk);
    gru_edges_atomic_noG<3><<<(n3 + 255) / 256, 256, 0, stream>>>(
        idx3, n3, h, Wih, bih, Whh, bhh, hk + (size_t)n1 * 32);
    gru_edges_atomic_noG<4><<<(n4 + 255) / 256, 256, 0, stream>>>(
        idx4, n4, h, Wih, bih, Whh, bhh, hk + (size_t)n1 * 64);
    mlp_out_fb<<<blocksN1, 256, 0, stream>>>(h, hk, n1, W1, b1, W2, b2, out);
}